// Round 2
// baseline (535.812 us; speedup 1.0000x reference)
//
#include <hip/hip_runtime.h>

// OTPE single timestep on MI355X.
// Inputs: x[8192], W[8192,4096], u[4096], E[8192,4096], R_hat[8192,4096],
//         g_bar[4096], ratio[1]  (all f32)
// Outputs (concat): s[4096], u_new[4096], E_new[8192,4096], R_new[8192,4096],
//                   g_bar_new[4096], ratio_new[1]
//
// Memory-bound: ~640 MB of mandatory HBM traffic -> ~102 us roofline at 6.3 TB/s.
// Round 1 = round 0 resubmit (bench infra flaked twice; no counters yet):
// (1) atomic-free split-K (per-chunk partials in ws, reduced in finalize;
//     no memset on critical path),
// (2) nontemporal loads/stores for all streamed-once data (W, E, R_hat,
//     E_new, R_new) to keep L2/L3 clean,
// (3) elemwise grid capped at 2048 blocks (256 CU x 8 wg/CU), grid-stride.

#define SIG_TAU 0.8807970779778823f  // sigmoid(2.0) in f32

typedef float f32x4 __attribute__((ext_vector_type(4)));

constexpr int N_IN  = 8192;
constexpr int N_OUT = 4096;
constexpr int NCG   = N_OUT / 4;          // 1024 float4 column-groups
constexpr int NCHUNK = 64;                // split-K chunks (1 MB partials)
constexpr int ROWS_PER_CHUNK = N_IN / NCHUNK;   // 128
constexpr int ROWS_PER_CHUNK_ATOM = 64;         // fallback path

// Output offsets (floats)
constexpr size_t OFF_S     = 0;
constexpr size_t OFF_U     = (size_t)N_OUT;                       // 4096
constexpr size_t OFF_E     = (size_t)2 * N_OUT;                   // 8192
constexpr size_t OFF_R     = OFF_E + (size_t)N_IN * N_OUT;        // 33562624
constexpr size_t OFF_G     = OFF_R + (size_t)N_IN * N_OUT;        // 67117056
constexpr size_t OFF_RATIO = OFF_G + (size_t)N_OUT;               // 67121152

// Split-K matvec, deterministic: each (cg, chunk) partial is written exactly
// once to ws. Coalesced float4 column reads; x[i] is wave-uniform scalar.
__global__ __launch_bounds__(256) void matvec_split(
    const float* __restrict__ x, const f32x4* __restrict__ W4,
    f32x4* __restrict__ part4) {
    const int cg    = blockIdx.x * 256 + threadIdx.x;   // 0..1023
    const int chunk = blockIdx.y;                        // 0..63
    const int row0  = chunk * ROWS_PER_CHUNK;
    f32x4 a = {0.f, 0.f, 0.f, 0.f};
#pragma unroll 8
    for (int r = 0; r < ROWS_PER_CHUNK; ++r) {
        const float xv = x[row0 + r];
        const f32x4 w  = __builtin_nontemporal_load(
            &W4[(size_t)(row0 + r) * NCG + cg]);
        a[0] = fmaf(xv, w[0], a[0]);
        a[1] = fmaf(xv, w[1], a[1]);
        a[2] = fmaf(xv, w[2], a[2]);
        a[3] = fmaf(xv, w[3], a[3]);
    }
    part4[(size_t)chunk * NCG + cg] = a;   // plain store, no atomics
}

// Fallback if ws is too small for partials: old atomicAdd path.
__global__ __launch_bounds__(256) void matvec_atomic(
    const float* __restrict__ x, const f32x4* __restrict__ W4,
    float* __restrict__ acc) {
    const int cg   = blockIdx.x * 256 + threadIdx.x;
    const int row0 = blockIdx.y * ROWS_PER_CHUNK_ATOM;
    f32x4 a = {0.f, 0.f, 0.f, 0.f};
#pragma unroll 8
    for (int r = 0; r < ROWS_PER_CHUNK_ATOM; ++r) {
        const float xv = x[row0 + r];
        const f32x4 w  = W4[(size_t)(row0 + r) * NCG + cg];
        a[0] = fmaf(xv, w[0], a[0]);
        a[1] = fmaf(xv, w[1], a[1]);
        a[2] = fmaf(xv, w[2], a[2]);
        a[3] = fmaf(xv, w[3], a[3]);
    }
    float* dst = acc + (size_t)cg * 4;
    atomicAdd(dst + 0, a[0]);
    atomicAdd(dst + 1, a[1]);
    atomicAdd(dst + 2, a[2]);
    atomicAdd(dst + 3, a[3]);
}

// Per-column: reduce split-K partials, spike, surrogate grad, soft reset,
// g_bar/ratio update. Partials (<=1 MB) are L2-resident.
__global__ __launch_bounds__(256) void finalize(
    const float* __restrict__ part, const int nchunks,
    const float* __restrict__ u, const float* __restrict__ g_bar,
    const float* __restrict__ ratio, float* __restrict__ out,
    float* __restrict__ sg_ws) {
    const int j = blockIdx.x * 256 + threadIdx.x;
    if (j >= N_OUT) return;
    float acc = 0.f;
    for (int c = 0; c < nchunks; ++c)
        acc += part[(size_t)c * N_OUT + j];   // coalesced across j

    const float u_pre = fmaf(SIG_TAU, u[j], acc);
    const float s     = (u_pre >= 1.0f) ? 1.0f : 0.0f;
    const float t     = 1.0f / fmaf(10.0f, fabsf(u_pre - 1.0f), 1.0f);
    const float sg    = t * t;                 // surrogate ds/du_pre
    const float u_new = u_pre - s;             // soft reset, V_TH=1

    const float r0        = SIG_TAU * ratio[0];
    const float ratio_new = r0 + 1.0f;
    const float r         = r0 / ratio_new;
    // ds_du_prev / sig_tau == sg
    const float g_new = fmaf(r, g_bar[j], (1.0f - r) * sg);

    out[OFF_S + j] = s;
    out[OFF_U + j] = u_new;
    out[OFF_G + j] = g_new;
    sg_ws[j] = sg;
    if (j == 0) out[OFF_RATIO] = ratio_new;
}

// Big streaming pass: E_new = sig_tau*E + x[i];
// R_new = sig_tau*R_hat + sg[j]*E_new  (== sig_tau*R_hat + ds_du_prev*E + x*sg)
// All big arrays nontemporal (streamed once, zero reuse); sg table + x cached.
__global__ __launch_bounds__(256) void elemwise(
    const float* __restrict__ x, const f32x4* __restrict__ E4,
    const f32x4* __restrict__ R4, const f32x4* __restrict__ sg4,
    f32x4* __restrict__ Enew4, f32x4* __restrict__ Rnew4) {
    const size_t total  = (size_t)N_IN * NCG;  // 8,388,608 float4 groups
    const size_t stride = (size_t)gridDim.x * blockDim.x;
    for (size_t idx = (size_t)blockIdx.x * blockDim.x + threadIdx.x;
         idx < total; idx += stride) {
        const int i  = (int)(idx >> 10);        // row (x index), NCG=1024
        const int cg = (int)(idx & (NCG - 1));  // column group
        const float xv = x[i];                  // broadcast within wave
        const f32x4 s4 = sg4[cg];               // 16 KB table, cache-resident
        const f32x4 e  = __builtin_nontemporal_load(&E4[idx]);
        const f32x4 rr = __builtin_nontemporal_load(&R4[idx]);
        f32x4 en, rn;
        en[0] = fmaf(SIG_TAU, e[0], xv);
        en[1] = fmaf(SIG_TAU, e[1], xv);
        en[2] = fmaf(SIG_TAU, e[2], xv);
        en[3] = fmaf(SIG_TAU, e[3], xv);
        rn[0] = fmaf(s4[0], en[0], SIG_TAU * rr[0]);
        rn[1] = fmaf(s4[1], en[1], SIG_TAU * rr[1]);
        rn[2] = fmaf(s4[2], en[2], SIG_TAU * rr[2]);
        rn[3] = fmaf(s4[3], en[3], SIG_TAU * rr[3]);
        __builtin_nontemporal_store(en, &Enew4[idx]);
        __builtin_nontemporal_store(rn, &Rnew4[idx]);
    }
}

extern "C" void kernel_launch(void* const* d_in, const int* in_sizes, int n_in,
                              void* d_out, int out_size, void* d_ws, size_t ws_size,
                              hipStream_t stream) {
    const float* x     = (const float*)d_in[0];
    const float* W     = (const float*)d_in[1];
    const float* u     = (const float*)d_in[2];
    const float* E     = (const float*)d_in[3];
    const float* R_hat = (const float*)d_in[4];
    const float* g_bar = (const float*)d_in[5];
    const float* ratio = (const float*)d_in[6];
    float* out = (float*)d_out;

    float* sg   = (float*)d_ws;            // [4096] surrogate grad
    float* part = sg + N_OUT;              // [NCHUNK*4096] split-K partials

    const size_t need = (size_t)(N_OUT + (size_t)NCHUNK * N_OUT) * sizeof(float);
    if (ws_size >= need) {
        // Deterministic split-K: no memset, no atomics.
        dim3 g1(NCG / 256, NCHUNK);        // (4, 64) = 256 blocks
        matvec_split<<<g1, 256, 0, stream>>>(x, (const f32x4*)W, (f32x4*)part);
        finalize<<<N_OUT / 256, 256, 0, stream>>>(
            part, NCHUNK, u, g_bar, ratio, out, sg);
    } else {
        // Fallback: atomic accumulation (ws poisoned 0xAA -> must zero).
        hipMemsetAsync(part, 0, N_OUT * sizeof(float), stream);
        dim3 g1(NCG / 256, N_IN / ROWS_PER_CHUNK_ATOM);  // (4, 128)
        matvec_atomic<<<g1, 256, 0, stream>>>(x, (const f32x4*)W, part);
        finalize<<<N_OUT / 256, 256, 0, stream>>>(
            part, 1, u, g_bar, ratio, out, sg);
    }

    // Grid-stride streaming pass: 2048 blocks = 256 CU x 8 wg/CU.
    elemwise<<<2048, 256, 0, stream>>>(
        x, (const f32x4*)E, (const f32x4*)R_hat, (const f32x4*)sg,
        (f32x4*)(out + OFF_E), (f32x4*)(out + OFF_R));
}